// Round 1
// baseline (743.827 us; speedup 1.0000x reference)
//
#include <hip/hip_runtime.h>

constexpr int NB = 256;   // batch
constexpr int NS = 64;    // seq len
constexpr int NN = 64;    // tree nodes
constexpr int NE = 300;   // embedding dim
constexpr int NH = 600;   // hidden dim
constexpr int LMAX = 22016; // max rows per relation list (level-3 worst case: 2*256*43)

// ---------------- workspace layout (float-indexed) ----------------
constexpr size_t OFF_H    = 0;                          // h/word state [2][NB][NN][NE]
constexpr size_t SZ_H     = (size_t)2*NB*NN*NE;
constexpr size_t OFF_PACC = OFF_H + SZ_H;               // parent accum [2][NB][16][NE]
constexpr size_t SZ_PACC  = (size_t)2*NB*16*NE;
constexpr size_t OFF_REP  = OFF_PACC + SZ_PACC;         // bag-of-words rep [2][NB][NE]
constexpr size_t SZ_REP   = (size_t)2*NB*NE;
constexpr size_t OFF_WT   = OFF_REP + SZ_REP;           // W_enc^T [3][NE][NE]
constexpr size_t SZ_WT    = (size_t)3*NE*NE;
constexpr size_t OFF_W0T  = OFF_WT + SZ_WT;             // W0^T [1800][600]
constexpr size_t SZ_W0T   = (size_t)6*NE*NH;
constexpr size_t OFF_W1T  = OFF_W0T + SZ_W0T;           // W1^T [600][600]
constexpr size_t SZ_W1T   = (size_t)NH*NH;
constexpr size_t OFF_W2T  = OFF_W1T + SZ_W1T;           // W2^T [600][600]
constexpr size_t SZ_W2T   = (size_t)NH*NH;
constexpr size_t OFF_X    = OFF_W2T + SZ_W2T;           // concat features [NB][1800]
constexpr size_t SZ_X     = (size_t)NB*6*NE;
constexpr size_t OFF_H1   = OFF_X + SZ_X;               // [NB][NH]
constexpr size_t OFF_H2   = OFF_H1 + (size_t)NB*NH;
constexpr size_t OFF_H3   = OFF_H2 + (size_t)NB*NH;
constexpr size_t OFF_LIST = OFF_H3 + (size_t)NB*NH;     // int [3][LMAX]
constexpr size_t OFF_CNT  = OFF_LIST + (size_t)3*LMAX;  // int [9] (3 levels x 3 relations)

// ---------------- kernels ----------------

__global__ __launch_bounds__(256)
void k_zero(float* pacc, int* cnt) {
  size_t i = (size_t)blockIdx.x*256 + threadIdx.x;
  for (size_t p = i; p < SZ_PACC; p += (size_t)gridDim.x*256) pacc[p] = 0.f;
  if (i < 9) cnt[i] = 0;
}

// Transpose all weight matrices (write-coalesced; strided reads hit L2).
__global__ __launch_bounds__(256)
void k_transpose(const float* Wenc, const float* W0, const float* W1, const float* W2,
                 float* WT, float* W0T, float* W1T, float* W2T) {
  int t = blockIdx.x*256 + threadIdx.x;
  if (t >= 2070000) return;
  if (t < 270000) {
    int r = t / 90000, rem = t % 90000, e = rem / 300, f = rem % 300;
    WT[t] = Wenc[r*90000 + f*300 + e];                 // WT[r][e][f] = W[r][f][e]
  } else if (t < 1350000) {
    int o = t - 270000, k = o / 600, j = o % 600;
    W0T[o] = W0[j*1800 + k];
  } else if (t < 1710000) {
    int o = t - 1350000, k = o / 600, j = o % 600;
    W1T[o] = W1[j*600 + k];
  } else {
    int o = t - 1710000, k = o / 600, j = o % 600;
    W2T[o] = W2[j*600 + k];
  }
}

// One block per (b, side): sum 64 embedding rows -> rep; build word/h state.
__global__ __launch_bounds__(256)
void k_gather(const int* px, const int* hx, const int* pwi, const int* hwi,
              const float* Etab, float* h, float* rep) {
  int b = blockIdx.x, s = blockIdx.y, tid = threadIdx.x;
  const int* xs = (s ? hx : px) + b*NS;
  const int* wi = (s ? hwi : pwi) + b*NN;
  __shared__ int xsh[NS];
  __shared__ int wish[NN];
  if (tid < NS) xsh[tid] = xs[tid];
  if (tid < NN) wish[tid] = wi[tid];
  __syncthreads();
  for (int e = tid; e < NE; e += 256) {
    float acc = 0.f;
    #pragma unroll 8
    for (int j = 0; j < NS; j++) acc += Etab[(size_t)xsh[j]*NE + e];
    rep[(size_t)(s*NB + b)*NE + e] = acc;
    for (int n = 0; n < NN; n++) {
      int w = wish[n];
      float v = (w < 0) ? 1.0f : Etab[(size_t)xsh[w]*NE + e];
      h[((size_t)(s*NB + b)*NN + n)*NE + e] = v;
    }
  }
}

// Compact transformed children of this level into per-relation row lists.
__global__ __launch_bounds__(256)
void k_list(const int* prel, const int* hrel, int c0, int nl, int lvl,
            int* lists, int* cnt) {
  int t = blockIdx.x*256 + threadIdx.x;
  int tot = 2*NB*nl;
  if (t >= tot) return;
  int j = t % nl;
  int b = (t / nl) % NB;
  int s = t / (nl*NB);
  int c = c0 + j;
  int r = (s ? hrel : prel)[b*NN + c];
  if (r >= 0 && r <= 2) {
    int pos = atomicAdd(&cnt[lvl*3 + r], 1);
    lists[r*LMAX + pos] = (s << 14) | (b << 6) | c;
  }
}

// Gathered GEMM: for each listed row i (relation r): t = W_r @ h_row,
// atomically accumulated into the parent's sum. A-tile in LDS (broadcast reads),
// W^T read coalesced over f.
__global__ __launch_bounds__(256)
void k_gemm(const float* h, const float* WT, const int* lists, const int* cnt,
            float* pacc, int lvl) {
  int r = blockIdx.y;
  int M = cnt[lvl*3 + r];
  int i0 = blockIdx.x * 16;
  if (i0 >= M) return;
  int rows = min(16, M - i0);
  __shared__ __align__(16) float A[16][NE];
  __shared__ int rcode[16];
  int tid = threadIdx.x;
  if (tid < rows) rcode[tid] = lists[r*LMAX + i0 + tid];
  __syncthreads();
  for (int flat = tid; flat < rows*NE; flat += 256) {
    int i = flat / NE, e = flat % NE;
    int code = rcode[i];
    int c = code & 63, bb = (code >> 6) & 255, s = code >> 14;
    A[i][e] = h[((size_t)(s*NB + bb)*NN + c)*NE + e];
  }
  __syncthreads();
  const float* Wr = WT + (size_t)r*NE*NE;
  for (int fc = 0; fc < 2; fc++) {
    int f = tid + fc*256;
    if (f >= NE) break;
    float acc[16];
    #pragma unroll
    for (int i = 0; i < 16; i++) acc[i] = 0.f;
    for (int e = 0; e < NE; e += 4) {
      float w0 = Wr[(e+0)*NE + f];
      float w1 = Wr[(e+1)*NE + f];
      float w2 = Wr[(e+2)*NE + f];
      float w3 = Wr[(e+3)*NE + f];
      #pragma unroll
      for (int i = 0; i < 16; i++) {
        const float4 a = *reinterpret_cast<const float4*>(&A[i][e]);
        acc[i] += a.x*w0 + a.y*w1 + a.z*w2 + a.w*w3;
      }
    }
    for (int i = 0; i < rows; i++) {
      int code = rcode[i];
      int c = code & 63, bb = (code >> 6) & 255, s = code >> 14;
      int p = (c - 1) >> 2;
      atomicAdd(&pacc[((size_t)(s*NB + bb)*16 + p)*NE + f], acc[i]);
    }
  }
}

// Parent update: sum = pacc (transformed children) + identity children (rel==-1/3),
// h[p] = relu(h[p] * sum/nc). h[p] pre-update == word[p] (each node updated once).
__global__ __launch_bounds__(256)
void k_parent(const int* prel, const int* hrel, float* h, const float* pacc, int p0) {
  int p = p0 + blockIdx.x;
  int b = blockIdx.y, s = blockIdx.z;
  int nc = min(4, 63 - 4*p);   // parent 15 has 3 children; all others 4
  const int* rel = (s ? hrel : prel) + b*NN;
  size_t hb = (size_t)(s*NB + b)*NN;
  float inv = 1.0f / (float)nc;
  for (int f = threadIdx.x; f < NE; f += 256) {
    float sum = pacc[((size_t)(s*NB + b)*16 + p)*NE + f];
    for (int j = 0; j < nc; j++) {
      int c = 4*p + 1 + j;
      int r = rel[c];
      if (r < 0 || r > 2) sum += h[(hb + c)*NE + f];
    }
    float mean = sum * inv;
    float hp = h[(hb + p)*NE + f];
    float v = hp * mean;
    h[(hb + p)*NE + f] = v > 0.f ? v : 0.f;
  }
}

// Build x = [p_rep, h_rep, p-h, p*h, psg-hsg, psg*hsg]
__global__ __launch_bounds__(256)
void k_concat(const float* rep, const float* h, float* x) {
  int t = blockIdx.x*256 + threadIdx.x;
  if (t >= NB*6*NE) return;
  int b = t / (6*NE), k = t % (6*NE);
  int seg = k / NE, e = k % NE;
  float pr = rep[(size_t)b*NE + e];
  float hr = rep[(size_t)(NB + b)*NE + e];
  float ps = h[((size_t)b*NN)*NE + e];          // premise root
  float hs = h[((size_t)(NB + b)*NN)*NE + e];   // hypothesis root
  float v;
  switch (seg) {
    case 0: v = pr; break;
    case 1: v = hr; break;
    case 2: v = pr - hr; break;
    case 3: v = pr * hr; break;
    case 4: v = ps - hs; break;
    default: v = ps * hs; break;
  }
  x[t] = v;
}

__global__ __launch_bounds__(256)
void k_bias(const float* bias, float* out) {
  int t = blockIdx.x*256 + threadIdx.x;
  if (t < NB*NH) out[t] = bias[t % NH];
}

// Split-K FC partial: block = 64b x 64j tile, thread = 4b x 4j, K-chunk per blockIdx.z.
// Partials atomically added onto bias-initialized out. relu applied on INPUT load.
__global__ __launch_bounds__(256)
void k_fc(const float* in, const float* WTm, float* out, int K, int kc, int relu_in) {
  __shared__ __align__(16) float xl[225*68];   // [kc][64 b, padded to 68]
  int b0 = blockIdx.x * 64;
  int j0 = blockIdx.y * 64;
  int k0 = blockIdx.z * kc;
  int tid = threadIdx.x;
  for (int flat = tid; flat < kc*64; flat += 256) {
    int bbp = flat / kc, k = flat % kc;
    float v = in[(size_t)(b0 + bbp)*K + k0 + k];
    if (relu_in) v = fmaxf(v, 0.f);
    xl[k*68 + bbp] = v;
  }
  __syncthreads();
  int tj = tid & 15, tb = tid >> 4;
  int j = j0 + tj*4;
  if (j + 3 >= NH) return;   // tail j-tile: only 6 of 16 tj groups active
  float acc[4][4];
  #pragma unroll
  for (int a = 0; a < 4; a++)
    #pragma unroll
    for (int bq = 0; bq < 4; bq++) acc[a][bq] = 0.f;
  for (int k = 0; k < kc; k++) {
    const float4 w  = *reinterpret_cast<const float4*>(&WTm[(size_t)(k0 + k)*NH + j]);
    const float4 xv = *reinterpret_cast<const float4*>(&xl[k*68 + tb*4]);
    acc[0][0] += xv.x*w.x; acc[0][1] += xv.x*w.y; acc[0][2] += xv.x*w.z; acc[0][3] += xv.x*w.w;
    acc[1][0] += xv.y*w.x; acc[1][1] += xv.y*w.y; acc[1][2] += xv.y*w.z; acc[1][3] += xv.y*w.w;
    acc[2][0] += xv.z*w.x; acc[2][1] += xv.z*w.y; acc[2][2] += xv.z*w.z; acc[2][3] += xv.z*w.w;
    acc[3][0] += xv.w*w.x; acc[3][1] += xv.w*w.y; acc[3][2] += xv.w*w.z; acc[3][3] += xv.w*w.w;
  }
  #pragma unroll
  for (int bi = 0; bi < 4; bi++) {
    #pragma unroll
    for (int ji = 0; ji < 4; ji++) {
      atomicAdd(&out[(size_t)(b0 + tb*4 + bi)*NH + j + ji], acc[bi][ji]);
    }
  }
}

// Final 600->3 layer; one wave per batch row; relu(h3) folded into load.
__global__ __launch_bounds__(64)
void k_out(const float* h3, const float* Wout, const float* bout, float* out) {
  int b = blockIdx.x, tid = threadIdx.x;
  float a0 = 0.f, a1 = 0.f, a2 = 0.f;
  for (int k = tid; k < NH; k += 64) {
    float xv = fmaxf(h3[(size_t)b*NH + k], 0.f);
    a0 += xv * Wout[k];
    a1 += xv * Wout[NH + k];
    a2 += xv * Wout[2*NH + k];
  }
  #pragma unroll
  for (int off = 32; off > 0; off >>= 1) {
    a0 += __shfl_down(a0, off, 64);
    a1 += __shfl_down(a1, off, 64);
    a2 += __shfl_down(a2, off, 64);
  }
  if (tid == 0) {
    out[b*3 + 0] = a0 + bout[0];
    out[b*3 + 1] = a1 + bout[1];
    out[b*3 + 2] = a2 + bout[2];
  }
}

// ---------------- launch ----------------
extern "C" void kernel_launch(void* const* d_in, const int* in_sizes, int n_in,
                              void* d_out, int out_size, void* d_ws, size_t ws_size,
                              hipStream_t stream) {
  const int*   px    = (const int*)d_in[0];
  const int*   hx    = (const int*)d_in[1];
  const int*   pwi   = (const int*)d_in[2];
  const int*   prel  = (const int*)d_in[3];
  const int*   hwi   = (const int*)d_in[4];
  const int*   hrel  = (const int*)d_in[5];
  // d_in[6]=parent, d_in[7]=level: fixed 4-ary tree, hardcoded
  const float* Etab  = (const float*)d_in[8];
  const float* Wenc  = (const float*)d_in[9];
  const float* W0w   = (const float*)d_in[10];
  const float* W0b   = (const float*)d_in[11];
  const float* W1w   = (const float*)d_in[12];
  const float* W1b   = (const float*)d_in[13];
  const float* W2w   = (const float*)d_in[14];
  const float* W2b   = (const float*)d_in[15];
  const float* Woutw = (const float*)d_in[16];
  const float* Woutb = (const float*)d_in[17];

  float* ws   = (float*)d_ws;
  float* h    = ws + OFF_H;
  float* pacc = ws + OFF_PACC;
  float* rep  = ws + OFF_REP;
  float* WT   = ws + OFF_WT;
  float* W0T  = ws + OFF_W0T;
  float* W1T  = ws + OFF_W1T;
  float* W2T  = ws + OFF_W2T;
  float* xb   = ws + OFF_X;
  float* h1   = ws + OFF_H1;
  float* h2   = ws + OFF_H2;
  float* h3   = ws + OFF_H3;
  int* lists  = (int*)(ws + OFF_LIST);
  int* cnt    = (int*)(ws + OFF_CNT);
  float* outp = (float*)d_out;

  dim3 blk(256);
  k_zero<<<dim3(4800), blk, 0, stream>>>(pacc, cnt);
  k_transpose<<<dim3((2070000 + 255)/256), blk, 0, stream>>>(Wenc, W0w, W1w, W2w,
                                                             WT, W0T, W1T, W2T);
  k_gather<<<dim3(NB, 2), blk, 0, stream>>>(px, hx, pwi, hwi, Etab, h, rep);

  // level-synchronous bottom-up: l=3,2,1
  const int c0s[3] = {21, 5, 1};
  const int nls[3] = {43, 16, 4};
  const int p0s[3] = {5, 1, 0};
  const int nps[3] = {11, 4, 1};
  for (int li = 0; li < 3; li++) {
    int tot = 2*NB*nls[li];
    k_list<<<dim3((tot + 255)/256), blk, 0, stream>>>(prel, hrel, c0s[li], nls[li], li,
                                                      lists, cnt);
    k_gemm<<<dim3((tot + 15)/16, 3), blk, 0, stream>>>(h, WT, lists, cnt, pacc, li);
    k_parent<<<dim3(nps[li], NB, 2), blk, 0, stream>>>(prel, hrel, h, pacc, p0s[li]);
  }

  k_concat<<<dim3((NB*6*NE + 255)/256), blk, 0, stream>>>(rep, h, xb);

  k_bias<<<dim3(600), blk, 0, stream>>>(W0b, h1);
  k_fc<<<dim3(4, 10, 8), blk, 0, stream>>>(xb, W0T, h1, 6*NE, 225, 0);
  k_bias<<<dim3(600), blk, 0, stream>>>(W1b, h2);
  k_fc<<<dim3(4, 10, 4), blk, 0, stream>>>(h1, W1T, h2, NH, 150, 1);
  k_bias<<<dim3(600), blk, 0, stream>>>(W2b, h3);
  k_fc<<<dim3(4, 10, 4), blk, 0, stream>>>(h2, W2T, h3, NH, 150, 1);
  k_out<<<dim3(NB), dim3(64), 0, stream>>>(h3, Woutw, Woutb, outp);
}

// Round 2
// 578.639 us; speedup vs baseline: 1.2855x; 1.2855x over previous
//
#include <hip/hip_runtime.h>

constexpr int NB = 256;   // batch
constexpr int NS = 64;    // seq len
constexpr int NN = 64;    // tree nodes
constexpr int NE = 300;   // embedding dim
constexpr int NH = 600;   // hidden dim
constexpr int LMAX = 22016; // max rows per relation list (level-3 worst case: 2*256*43)

typedef __attribute__((ext_vector_type(8))) short bf16x8;
typedef __attribute__((ext_vector_type(4))) float f32x4;

// ---------------- workspace layout (float-indexed) ----------------
constexpr size_t OFF_H    = 0;                          // h state fp32 [2][NB][NN][NE]
constexpr size_t SZ_H     = (size_t)2*NB*NN*NE;
constexpr size_t OFF_PACC = OFF_H + SZ_H;               // parent accum [2][NB][16][NE]
constexpr size_t SZ_PACC  = (size_t)2*NB*16*NE;
constexpr size_t OFF_REP  = OFF_PACC + SZ_PACC;         // bag-of-words rep [2][NB][NE]
constexpr size_t SZ_REP   = (size_t)2*NB*NE;
constexpr size_t OFF_WBF  = OFF_REP + SZ_REP;           // W_enc bf16 B-frag swizzled
constexpr size_t SZ_WBF   = (size_t)3*20*10*64*8/2;     // 307200 ushorts = 153600 floats
constexpr size_t OFF_W0T  = OFF_WBF + SZ_WBF;           // W0^T [1800][600]
constexpr size_t SZ_W0T   = (size_t)6*NE*NH;
constexpr size_t OFF_W1T  = OFF_W0T + SZ_W0T;           // W1^T [600][600]
constexpr size_t SZ_W1T   = (size_t)NH*NH;
constexpr size_t OFF_W2T  = OFF_W1T + SZ_W1T;           // W2^T [600][600]
constexpr size_t SZ_W2T   = (size_t)NH*NH;
constexpr size_t OFF_X    = OFF_W2T + SZ_W2T;           // concat features [NB][1800]
constexpr size_t SZ_X     = (size_t)NB*6*NE;
constexpr size_t OFF_H1   = OFF_X + SZ_X;               // [NB][NH]
constexpr size_t OFF_H2   = OFF_H1 + (size_t)NB*NH;
constexpr size_t OFF_H3   = OFF_H2 + (size_t)NB*NH;
constexpr size_t OFF_LIST = OFF_H3 + (size_t)NB*NH;     // int [3][LMAX]
constexpr size_t OFF_CNT  = OFF_LIST + (size_t)3*LMAX;  // int [9] (3 levels x 3 relations)

__device__ __forceinline__ ushort f2bf(float x) {
  unsigned u = __float_as_uint(x);
  unsigned r = (u + 0x7FFFu + ((u >> 16) & 1u)) >> 16;   // RNE
  return (ushort)r;
}

// ---------------- kernels ----------------

// Fused prologue: zero pacc+cnt, bias-init h1/h2/h3, swizzle W_enc into bf16
// B-fragment order: Wbf[((nt*10+ks)*64+lane)*8 + j] = bf16(W_enc[r][f][e]),
// f = nt*16+(lane&15), e = ks*32+(lane>>4)*8+j, zero-padded past 300.
constexpr int PACC4 = (int)(SZ_PACC/4);   // 614400 float4 stores
constexpr int BIAS4 = NB*NH/4;            // 38400 per layer
constexpr int NSWZ  = 3*20*10*64;         // 38400 lane-frags

__global__ __launch_bounds__(256)
void k_prep(const float* Wenc, const float* b0, const float* b1, const float* b2,
            float* pacc, float* h1, float* h2, float* h3, ushort* Wbf, int* cnt) {
  int t = blockIdx.x*256 + threadIdx.x;
  if (t < PACC4) {
    reinterpret_cast<float4*>(pacc)[t] = float4{0.f,0.f,0.f,0.f};
    return;
  }
  t -= PACC4;
  if (t < 3*BIAS4) {
    int layer = t / BIAS4, i = t % BIAS4;
    const float* b = layer==0 ? b0 : (layer==1 ? b1 : b2);
    float* hx = layer==0 ? h1 : (layer==1 ? h2 : h3);
    reinterpret_cast<float4*>(hx)[i] = reinterpret_cast<const float4*>(b)[i % 150];
    return;
  }
  t -= 3*BIAS4;
  if (t < NSWZ) {
    int lane = t & 63, rest = t >> 6;
    int ks = rest % 10, rnt = rest / 10, nt = rnt % 20, r = rnt / 20;
    int f = nt*16 + (lane & 15), e0 = ks*32 + (lane >> 4)*8;
    ushort v[8];
    #pragma unroll
    for (int j = 0; j < 8; j++) {
      int e = e0 + j;
      v[j] = (f < NE && e < NE) ? f2bf(Wenc[((size_t)r*NE + f)*NE + e]) : (ushort)0;
    }
    *reinterpret_cast<int4*>(&Wbf[(size_t)t*8]) = *reinterpret_cast<const int4*>(v);
    return;
  }
  t -= NSWZ;
  if (t < 9) cnt[t] = 0;
}

// Tiled LDS transpose for the three MLP weight matrices (coalesced both sides).
__global__ __launch_bounds__(256)
void k_transpose(const float* W0, const float* W1, const float* W2,
                 float* W0T, float* W1T, float* W2T) {
  __shared__ float tile[32][33];
  int z = blockIdx.z;
  const float* W = z==0 ? W0 : (z==1 ? W1 : W2);
  float* WT = z==0 ? W0T : (z==1 ? W1T : W2T);
  int K = z==0 ? 1800 : 600;               // W [600][K] -> WT [K][600]
  int k0 = blockIdx.x * 32, j0 = blockIdx.y * 32;
  if (k0 >= K) return;
  int tx = threadIdx.x & 31, ty = threadIdx.x >> 5;
  for (int yy = ty; yy < 32; yy += 8) {
    int j = j0 + yy, k = k0 + tx;
    if (j < 600 && k < K) tile[yy][tx] = W[(size_t)j*K + k];
  }
  __syncthreads();
  for (int yy = ty; yy < 32; yy += 8) {
    int k = k0 + yy, j = j0 + tx;
    if (k < K && j < 600) WT[(size_t)k*600 + j] = tile[tx][yy];
  }
}

// One block per (b, side): sum 64 embedding rows -> rep; build word/h state.
__global__ __launch_bounds__(256)
void k_gather(const int* px, const int* hx, const int* pwi, const int* hwi,
              const float* Etab, float* h, float* rep) {
  int b = blockIdx.x, s = blockIdx.y, tid = threadIdx.x;
  const int* xs = (s ? hx : px) + b*NS;
  const int* wi = (s ? hwi : pwi) + b*NN;
  __shared__ int xsh[NS];
  __shared__ int wish[NN];
  if (tid < NS) xsh[tid] = xs[tid];
  if (tid < NN) wish[tid] = wi[tid];
  __syncthreads();
  for (int e = tid; e < NE; e += 256) {
    float acc = 0.f;
    #pragma unroll 8
    for (int j = 0; j < NS; j++) acc += Etab[(size_t)xsh[j]*NE + e];
    rep[(size_t)(s*NB + b)*NE + e] = acc;
    for (int n = 0; n < NN; n++) {
      int w = wish[n];
      float v = (w < 0) ? 1.0f : Etab[(size_t)xsh[w]*NE + e];
      h[((size_t)(s*NB + b)*NN + n)*NE + e] = v;
    }
  }
}

// Compact transformed children of this level into per-relation row lists.
__global__ __launch_bounds__(256)
void k_list(const int* prel, const int* hrel, int c0, int nl, int lvl,
            int* lists, int* cnt) {
  int t = blockIdx.x*256 + threadIdx.x;
  int tot = 2*NB*nl;
  if (t >= tot) return;
  int j = t % nl;
  int b = (t / nl) % NB;
  int s = t / (nl*NB);
  int c = c0 + j;
  int r = (s ? hrel : prel)[b*NN + c];
  if (r >= 0 && r <= 2) {
    int pos = atomicAdd(&cnt[lvl*3 + r], 1);
    lists[r*LMAX + pos] = (s << 14) | (b << 6) | c;
  }
}

// MFMA gathered GEMM: 32 listed rows x 320(f,padded) per block, K=320 padded.
// A: h rows fp32->bf16 staged in LDS (row stride 328 -> free 2-way bank alias).
// B: pre-swizzled bf16 frags, one coalesced 16B global load per lane per MFMA.
// Output atomically accumulated into the parent's fp32 sum.
__global__ __launch_bounds__(256)
void k_gemm(const float* h, const ushort* Wbf, const int* lists, const int* cnt,
            float* pacc, int lvl) {
  int r = blockIdx.y;
  int M = cnt[lvl*3 + r];
  int i0 = blockIdx.x * 32;
  if (i0 >= M) return;
  int rows = min(32, M - i0);
  __shared__ ushort A[32*328];
  __shared__ int rcode[32];
  int tid = threadIdx.x;
  if (tid < rows) rcode[tid] = lists[r*LMAX + i0 + tid];
  __syncthreads();
  // stage A: fp32 -> bf16, 4 elems per chunk; zero K-pad region e in [300,320)
  for (int flat = tid; flat < rows*75; flat += 256) {
    int i = flat / 75, c = flat % 75;
    int code = rcode[i];
    int cn = code & 63, bb = (code >> 6) & 255, s = code >> 14;
    const float4 v = *reinterpret_cast<const float4*>(
        &h[((size_t)(s*NB + bb)*NN + cn)*NE + c*4]);
    ushort4 o; o.x = f2bf(v.x); o.y = f2bf(v.y); o.z = f2bf(v.z); o.w = f2bf(v.w);
    *reinterpret_cast<ushort4*>(&A[i*328 + c*4]) = o;
  }
  for (int flat = tid; flat < rows*10; flat += 256) {
    int i = flat / 10, c = flat % 10;
    *reinterpret_cast<unsigned*>(&A[i*328 + 300 + c*2]) = 0u;
  }
  __syncthreads();

  int wave = tid >> 6, lane = tid & 63;
  int mrow = lane & 15, quad = lane >> 4;
  // hoist all A fragments (shared by every n-tile this wave touches)
  bf16x8 af[2][10];
  #pragma unroll
  for (int sub = 0; sub < 2; sub++)
    #pragma unroll
    for (int ks = 0; ks < 10; ks++)
      af[sub][ks] = *reinterpret_cast<const bf16x8*>(
          &A[(sub*16 + mrow)*328 + ks*32 + quad*8]);

  f32x4 acc[5][2];
  #pragma unroll
  for (int a = 0; a < 5; a++)
    #pragma unroll
    for (int b2 = 0; b2 < 2; b2++)
      acc[a][b2] = f32x4{0.f,0.f,0.f,0.f};

  const ushort* Wb = Wbf + (size_t)r*20*10*64*8;
  #pragma unroll
  for (int t5 = 0; t5 < 5; t5++) {
    int nt = wave + t5*4;
    #pragma unroll
    for (int ks = 0; ks < 10; ks++) {
      bf16x8 bf = *reinterpret_cast<const bf16x8*>(&Wb[((size_t)(nt*10 + ks)*64 + lane)*8]);
      acc[t5][0] = __builtin_amdgcn_mfma_f32_16x16x32_bf16(af[0][ks], bf, acc[t5][0], 0, 0, 0);
      acc[t5][1] = __builtin_amdgcn_mfma_f32_16x16x32_bf16(af[1][ks], bf, acc[t5][1], 0, 0, 0);
    }
  }

  // epilogue: C/D layout col(n)=lane&15, row(m)=quad*4+reg
  #pragma unroll
  for (int t5 = 0; t5 < 5; t5++) {
    int nt = wave + t5*4;
    int f = nt*16 + mrow;
    if (f >= NE) continue;
    #pragma unroll
    for (int sub = 0; sub < 2; sub++) {
      #pragma unroll
      for (int reg = 0; reg < 4; reg++) {
        int ml = sub*16 + quad*4 + reg;
        if (ml < rows) {
          int code = rcode[ml];
          int cn = code & 63, bb = (code >> 6) & 255, s = code >> 14;
          int p = (cn - 1) >> 2;
          atomicAdd(&pacc[((size_t)(s*NB + bb)*16 + p)*NE + f], acc[t5][sub][reg]);
        }
      }
    }
  }
}

// Parent update: sum = pacc (transformed children) + identity children,
// h[p] = relu(h[p] * sum/nc).
__global__ __launch_bounds__(256)
void k_parent(const int* prel, const int* hrel, float* h, const float* pacc, int p0) {
  int p = p0 + blockIdx.x;
  int b = blockIdx.y, s = blockIdx.z;
  int nc = min(4, 63 - 4*p);
  const int* rel = (s ? hrel : prel) + b*NN;
  size_t hb = (size_t)(s*NB + b)*NN;
  float inv = 1.0f / (float)nc;
  for (int f = threadIdx.x; f < NE; f += 256) {
    float sum = pacc[((size_t)(s*NB + b)*16 + p)*NE + f];
    for (int j = 0; j < nc; j++) {
      int c = 4*p + 1 + j;
      int r = rel[c];
      if (r < 0 || r > 2) sum += h[(hb + c)*NE + f];
    }
    float mean = sum * inv;
    float hp = h[(hb + p)*NE + f];
    float v = hp * mean;
    h[(hb + p)*NE + f] = v > 0.f ? v : 0.f;
  }
}

// Build x = [p_rep, h_rep, p-h, p*h, psg-hsg, psg*hsg]
__global__ __launch_bounds__(256)
void k_concat(const float* rep, const float* h, float* x) {
  int t = blockIdx.x*256 + threadIdx.x;
  if (t >= NB*6*NE) return;
  int b = t / (6*NE), k = t % (6*NE);
  int seg = k / NE, e = k % NE;
  float pr = rep[(size_t)b*NE + e];
  float hr = rep[(size_t)(NB + b)*NE + e];
  float ps = h[((size_t)b*NN)*NE + e];
  float hs = h[((size_t)(NB + b)*NN)*NE + e];
  float v;
  switch (seg) {
    case 0: v = pr; break;
    case 1: v = hr; break;
    case 2: v = pr - hr; break;
    case 3: v = pr * hr; break;
    case 4: v = ps - hs; break;
    default: v = ps * hs; break;
  }
  x[t] = v;
}

// Split-K FC partial: block = 64b x 64j tile, thread = 4b x 4j, K-chunk per z.
// Partials atomicAdd onto bias-initialized out. relu applied on INPUT load.
__global__ __launch_bounds__(256)
void k_fc(const float* in, const float* WTm, float* out, int K, int kc, int relu_in) {
  __shared__ __align__(16) float xl[225*68];
  int b0 = blockIdx.x * 64;
  int j0 = blockIdx.y * 64;
  int k0 = blockIdx.z * kc;
  int tid = threadIdx.x;
  for (int flat = tid; flat < kc*64; flat += 256) {
    int bbp = flat / kc, k = flat % kc;
    float v = in[(size_t)(b0 + bbp)*K + k0 + k];
    if (relu_in) v = fmaxf(v, 0.f);
    xl[k*68 + bbp] = v;
  }
  __syncthreads();
  int tj = tid & 15, tb = tid >> 4;
  int j = j0 + tj*4;
  if (j + 3 >= NH) return;
  float acc[4][4];
  #pragma unroll
  for (int a = 0; a < 4; a++)
    #pragma unroll
    for (int bq = 0; bq < 4; bq++) acc[a][bq] = 0.f;
  for (int k = 0; k < kc; k++) {
    const float4 w  = *reinterpret_cast<const float4*>(&WTm[(size_t)(k0 + k)*NH + j]);
    const float4 xv = *reinterpret_cast<const float4*>(&xl[k*68 + tb*4]);
    acc[0][0] += xv.x*w.x; acc[0][1] += xv.x*w.y; acc[0][2] += xv.x*w.z; acc[0][3] += xv.x*w.w;
    acc[1][0] += xv.y*w.x; acc[1][1] += xv.y*w.y; acc[1][2] += xv.y*w.z; acc[1][3] += xv.y*w.w;
    acc[2][0] += xv.z*w.x; acc[2][1] += xv.z*w.y; acc[2][2] += xv.z*w.z; acc[2][3] += xv.z*w.w;
    acc[3][0] += xv.w*w.x; acc[3][1] += xv.w*w.y; acc[3][2] += xv.w*w.z; acc[3][3] += xv.w*w.w;
  }
  #pragma unroll
  for (int bi = 0; bi < 4; bi++) {
    #pragma unroll
    for (int ji = 0; ji < 4; ji++) {
      atomicAdd(&out[(size_t)(b0 + tb*4 + bi)*NH + j + ji], acc[bi][ji]);
    }
  }
}

// Final 600->3 layer; one wave per batch row; relu(h3) folded into load.
__global__ __launch_bounds__(64)
void k_out(const float* h3, const float* Wout, const float* bout, float* out) {
  int b = blockIdx.x, tid = threadIdx.x;
  float a0 = 0.f, a1 = 0.f, a2 = 0.f;
  for (int k = tid; k < NH; k += 64) {
    float xv = fmaxf(h3[(size_t)b*NH + k], 0.f);
    a0 += xv * Wout[k];
    a1 += xv * Wout[NH + k];
    a2 += xv * Wout[2*NH + k];
  }
  #pragma unroll
  for (int off = 32; off > 0; off >>= 1) {
    a0 += __shfl_down(a0, off, 64);
    a1 += __shfl_down(a1, off, 64);
    a2 += __shfl_down(a2, off, 64);
  }
  if (tid == 0) {
    out[b*3 + 0] = a0 + bout[0];
    out[b*3 + 1] = a1 + bout[1];
    out[b*3 + 2] = a2 + bout[2];
  }
}

// ---------------- launch ----------------
extern "C" void kernel_launch(void* const* d_in, const int* in_sizes, int n_in,
                              void* d_out, int out_size, void* d_ws, size_t ws_size,
                              hipStream_t stream) {
  const int*   px    = (const int*)d_in[0];
  const int*   hx    = (const int*)d_in[1];
  const int*   pwi   = (const int*)d_in[2];
  const int*   prel  = (const int*)d_in[3];
  const int*   hwi   = (const int*)d_in[4];
  const int*   hrel  = (const int*)d_in[5];
  // d_in[6]=parent, d_in[7]=level: fixed 4-ary tree, hardcoded
  const float* Etab  = (const float*)d_in[8];
  const float* Wenc  = (const float*)d_in[9];
  const float* W0w   = (const float*)d_in[10];
  const float* W0b   = (const float*)d_in[11];
  const float* W1w   = (const float*)d_in[12];
  const float* W1b   = (const float*)d_in[13];
  const float* W2w   = (const float*)d_in[14];
  const float* W2b   = (const float*)d_in[15];
  const float* Woutw = (const float*)d_in[16];
  const float* Woutb = (const float*)d_in[17];

  float* ws   = (float*)d_ws;
  float* h    = ws + OFF_H;
  float* pacc = ws + OFF_PACC;
  float* rep  = ws + OFF_REP;
  ushort* Wbf = (ushort*)(ws + OFF_WBF);
  float* W0T  = ws + OFF_W0T;
  float* W1T  = ws + OFF_W1T;
  float* W2T  = ws + OFF_W2T;
  float* xb   = ws + OFF_X;
  float* h1   = ws + OFF_H1;
  float* h2   = ws + OFF_H2;
  float* h3   = ws + OFF_H3;
  int* lists  = (int*)(ws + OFF_LIST);
  int* cnt    = (int*)(ws + OFF_CNT);
  float* outp = (float*)d_out;

  dim3 blk(256);
  constexpr int PREP_ITEMS = PACC4 + 3*BIAS4 + NSWZ + 9;
  k_prep<<<dim3((PREP_ITEMS + 255)/256), blk, 0, stream>>>(
      Wenc, W0b, W1b, W2b, pacc, h1, h2, h3, Wbf, cnt);
  k_transpose<<<dim3(57, 19, 3), blk, 0, stream>>>(W0w, W1w, W2w, W0T, W1T, W2T);
  k_gather<<<dim3(NB, 2), blk, 0, stream>>>(px, hx, pwi, hwi, Etab, h, rep);

  // level-synchronous bottom-up: l=3,2,1
  const int c0s[3] = {21, 5, 1};
  const int nls[3] = {43, 16, 4};
  const int p0s[3] = {5, 1, 0};
  const int nps[3] = {11, 4, 1};
  for (int li = 0; li < 3; li++) {
    int tot = 2*NB*nls[li];
    k_list<<<dim3((tot + 255)/256), blk, 0, stream>>>(prel, hrel, c0s[li], nls[li], li,
                                                      lists, cnt);
    k_gemm<<<dim3((tot + 31)/32, 3), blk, 0, stream>>>(h, Wbf, lists, cnt, pacc, li);
    k_parent<<<dim3(nps[li], NB, 2), blk, 0, stream>>>(prel, hrel, h, pacc, p0s[li]);
  }

  k_concat<<<dim3((NB*6*NE + 255)/256), blk, 0, stream>>>(rep, h, xb);

  k_fc<<<dim3(4, 10, 8), blk, 0, stream>>>(xb, W0T, h1, 6*NE, 225, 0);
  k_fc<<<dim3(4, 10, 4), blk, 0, stream>>>(h1, W1T, h2, NH, 150, 1);
  k_fc<<<dim3(4, 10, 4), blk, 0, stream>>>(h2, W2T, h3, NH, 150, 1);
  k_out<<<dim3(NB), dim3(64), 0, stream>>>(h3, Woutw, Woutb, outp);
}

// Round 3
// 449.268 us; speedup vs baseline: 1.6556x; 1.2880x over previous
//
#include <hip/hip_runtime.h>

constexpr int NB = 256;   // batch
constexpr int NS = 64;    // seq len
constexpr int NN = 64;    // tree nodes
constexpr int NE = 300;   // embedding dim
constexpr int NH = 600;   // hidden dim

typedef __attribute__((ext_vector_type(8))) short bf16x8;
typedef __attribute__((ext_vector_type(4))) float f32x4;

// per-(level,rel) list capacities: level idx 0 => tree level 3 (children 21..63),
// 1 => level 2 (5..20), 2 => level 1 (1..4)
__device__ __host__ constexpr int cap_of(int li)  { return li==0 ? 22016 : (li==1 ? 8192 : 2048); }
__device__ __host__ constexpr int base_of(int li) { return li==0 ? 0 : (li==1 ? 66048 : 90624); }
constexpr int LIST_TOT = 96768;  // 3*22016 + 3*8192 + 3*2048
constexpr int CNT_TOT  = 9*32;   // 9 counters padded to separate cache lines

// ---------------- workspace layout (float-indexed) ----------------
constexpr size_t OFF_H    = 0;                          // h state fp32 [2][NB][NN][NE]
constexpr size_t SZ_H     = (size_t)2*NB*NN*NE;
constexpr size_t OFF_PACC = OFF_H + SZ_H;               // parent accum [2][NB][16][NE]
constexpr size_t SZ_PACC  = (size_t)2*NB*16*NE;
constexpr size_t OFF_REP  = OFF_PACC + SZ_PACC;         // bag-of-words rep [2][NB][NE]
constexpr size_t SZ_REP   = (size_t)2*NB*NE;
constexpr size_t OFF_WBF  = OFF_REP + SZ_REP;           // W_enc bf16 B-frag swizzled
constexpr size_t SZ_WBF   = (size_t)3*20*10*64*8/2;     // 307200 ushorts = 153600 floats
constexpr size_t OFF_W0T  = OFF_WBF + SZ_WBF;           // W0^T [1800][600]
constexpr size_t SZ_W0T   = (size_t)6*NE*NH;
constexpr size_t OFF_W1T  = OFF_W0T + SZ_W0T;           // W1^T [600][600]
constexpr size_t SZ_W1T   = (size_t)NH*NH;
constexpr size_t OFF_W2T  = OFF_W1T + SZ_W1T;           // W2^T [600][600]
constexpr size_t SZ_W2T   = (size_t)NH*NH;
constexpr size_t OFF_X    = OFF_W2T + SZ_W2T;           // concat features [NB][1800]
constexpr size_t SZ_X     = (size_t)NB*6*NE;
constexpr size_t OFF_H1   = OFF_X + SZ_X;               // [NB][NH]
constexpr size_t OFF_H2   = OFF_H1 + (size_t)NB*NH;
constexpr size_t OFF_H3   = OFF_H2 + (size_t)NB*NH;
constexpr size_t OFF_LIST = OFF_H3 + (size_t)NB*NH;     // int [LIST_TOT]
constexpr size_t OFF_CNT  = OFF_LIST + LIST_TOT;        // int [CNT_TOT]

__device__ __forceinline__ ushort f2bf(float x) {
  unsigned u = __float_as_uint(x);
  unsigned r = (u + 0x7FFFu + ((u >> 16) & 1u)) >> 16;   // RNE
  return (ushort)r;
}

// ---------------- kernels ----------------

// Fused prologue: zero pacc+cnt, bias-init h1/h2/h3, swizzle W_enc into bf16
// B-fragment order: Wbf[((nt*10+ks)*64+lane)*8 + j] = bf16(W_enc[r][f][e]),
// f = nt*16+(lane&15), e = ks*32+(lane>>4)*8+j, zero-padded past 300.
constexpr int PACC4 = (int)(SZ_PACC/4);   // 614400 float4 stores
constexpr int BIAS4 = NB*NH/4;            // 38400 per layer
constexpr int NSWZ  = 3*20*10*64;         // 38400 lane-frags

__global__ __launch_bounds__(256)
void k_prep(const float* __restrict__ Wenc, const float* __restrict__ b0,
            const float* __restrict__ b1, const float* __restrict__ b2,
            float* __restrict__ pacc, float* __restrict__ h1, float* __restrict__ h2,
            float* __restrict__ h3, ushort* __restrict__ Wbf, int* __restrict__ cnt) {
  int t = blockIdx.x*256 + threadIdx.x;
  if (t < PACC4) {
    reinterpret_cast<float4*>(pacc)[t] = float4{0.f,0.f,0.f,0.f};
    return;
  }
  t -= PACC4;
  if (t < 3*BIAS4) {
    int layer = t / BIAS4, i = t % BIAS4;
    const float* b = layer==0 ? b0 : (layer==1 ? b1 : b2);
    float* hx = layer==0 ? h1 : (layer==1 ? h2 : h3);
    reinterpret_cast<float4*>(hx)[i] = reinterpret_cast<const float4*>(b)[i % 150];
    return;
  }
  t -= 3*BIAS4;
  if (t < NSWZ) {
    int lane = t & 63, rest = t >> 6;
    int ks = rest % 10, rnt = rest / 10, nt = rnt % 20, r = rnt / 20;
    int f = nt*16 + (lane & 15), e0 = ks*32 + (lane >> 4)*8;
    ushort v[8];
    #pragma unroll
    for (int j = 0; j < 8; j++) {
      int e = e0 + j;
      v[j] = (f < NE && e < NE) ? f2bf(Wenc[((size_t)r*NE + f)*NE + e]) : (ushort)0;
    }
    *reinterpret_cast<int4*>(&Wbf[(size_t)t*8]) = *reinterpret_cast<const int4*>(v);
    return;
  }
  t -= NSWZ;
  if (t < CNT_TOT) cnt[t] = 0;
}

// Tiled LDS transpose for the three MLP weight matrices (coalesced both sides).
__global__ __launch_bounds__(256)
void k_transpose(const float* __restrict__ W0, const float* __restrict__ W1,
                 const float* __restrict__ W2, float* __restrict__ W0T,
                 float* __restrict__ W1T, float* __restrict__ W2T) {
  __shared__ float tile[32][33];
  int z = blockIdx.z;
  const float* W = z==0 ? W0 : (z==1 ? W1 : W2);
  float* WT = z==0 ? W0T : (z==1 ? W1T : W2T);
  int K = z==0 ? 1800 : 600;               // W [600][K] -> WT [K][600]
  int k0 = blockIdx.x * 32, j0 = blockIdx.y * 32;
  if (k0 >= K) return;
  int tx = threadIdx.x & 31, ty = threadIdx.x >> 5;
  for (int yy = ty; yy < 32; yy += 8) {
    int j = j0 + yy, k = k0 + tx;
    if (j < 600 && k < K) tile[yy][tx] = W[(size_t)j*K + k];
  }
  __syncthreads();
  for (int yy = ty; yy < 32; yy += 8) {
    int k = k0 + yy, j = j0 + tx;
    if (k < K && j < 600) WT[(size_t)k*600 + j] = tile[tx][yy];
  }
}

// One block per (b, side), 320 threads: e = tid (300 active lanes).
// Sum 64 embedding rows -> rep; build word/h state.
__global__ __launch_bounds__(320)
void k_gather(const int* __restrict__ px, const int* __restrict__ hx,
              const int* __restrict__ pwi, const int* __restrict__ hwi,
              const float* __restrict__ Etab, float* __restrict__ h,
              float* __restrict__ rep) {
  int b = blockIdx.x, s = blockIdx.y, tid = threadIdx.x;
  const int* xs = (s ? hx : px) + b*NS;
  const int* wi = (s ? hwi : pwi) + b*NN;
  __shared__ int xsh[NS];
  __shared__ int wish[NN];
  if (tid < NS) xsh[tid] = xs[tid];
  else if (tid >= 64 && tid < 64 + NN) wish[tid - 64] = wi[tid - 64];
  __syncthreads();
  int e = tid;
  if (e >= NE) return;
  float acc = 0.f;
  #pragma unroll 8
  for (int j = 0; j < NS; j++) acc += Etab[(size_t)xsh[j]*NE + e];
  rep[(size_t)(s*NB + b)*NE + e] = acc;
  for (int n = 0; n < NN; n++) {
    int w = wish[n];
    float v = (w < 0) ? 1.0f : Etab[(size_t)xsh[w]*NE + e];
    h[((size_t)(s*NB + b)*NN + n)*NE + e] = v;
  }
}

// Compact transformed children of ALL levels into per-(level,rel) lists.
// Wave-aggregated: one atomic per (wave, non-empty bucket) instead of per lane.
__global__ __launch_bounds__(256)
void k_list(const int* __restrict__ prel, const int* __restrict__ hrel,
            int* __restrict__ lists, int* __restrict__ cnt) {
  int t = blockIdx.x*256 + threadIdx.x;   // exactly 2*256*63 = 32256 threads
  int c = 1 + (t % 63);
  int b = (t / 63) % NB;
  int s = t / (63*NB);
  int r = (s ? hrel : prel)[b*NN + c];
  int li = (c >= 21) ? 0 : (c >= 5 ? 1 : 2);
  int bucket = (r >= 0 && r <= 2) ? li*3 + r : -1;
  int code = (s << 14) | (b << 6) | c;
  int lane = threadIdx.x & 63;
  #pragma unroll
  for (int k = 0; k < 9; k++) {
    unsigned long long mask = __ballot(bucket == k);
    if (mask == 0ull) continue;                       // wave-uniform
    int leader = __ffsll((unsigned long long)mask) - 1;
    int base = 0;
    if (lane == leader) base = atomicAdd(&cnt[k*32], (int)__popcll(mask));
    base = __shfl(base, leader, 64);
    if (bucket == k) {
      int pos = base + (int)__popcll(mask & ((1ull << lane) - 1ull));
      lists[base_of(k/3) + (k%3)*cap_of(k/3) + pos] = code;
    }
  }
}

// MFMA gathered GEMM: 32 listed rows x 320(f,padded) per block, K=320 padded.
// A: h rows fp32->bf16 staged in LDS (row stride 328 -> free 2-way bank alias).
// B: pre-swizzled bf16 frags, one coalesced 16B global load per lane per MFMA.
// Output atomically accumulated into the parent's fp32 sum.
__global__ __launch_bounds__(256)
void k_gemm(const float* __restrict__ h, const ushort* __restrict__ Wbf,
            const int* __restrict__ lists, const int* __restrict__ cnt,
            float* __restrict__ pacc, int lvl) {
  int r = blockIdx.y;
  int M = cnt[(lvl*3 + r)*32];
  int i0 = blockIdx.x * 32;
  if (i0 >= M) return;
  int rows = min(32, M - i0);
  __shared__ ushort A[32*328];
  __shared__ int rcode[32];
  int tid = threadIdx.x;
  if (tid < rows) rcode[tid] = lists[base_of(lvl) + r*cap_of(lvl) + i0 + tid];
  __syncthreads();
  // stage A: fp32 -> bf16, 4 elems per chunk; zero K-pad region e in [300,320)
  for (int flat = tid; flat < rows*75; flat += 256) {
    int i = flat / 75, c = flat % 75;
    int code = rcode[i];
    int cn = code & 63, bb = (code >> 6) & 255, s = code >> 14;
    const float4 v = *reinterpret_cast<const float4*>(
        &h[((size_t)(s*NB + bb)*NN + cn)*NE + c*4]);
    ushort4 o; o.x = f2bf(v.x); o.y = f2bf(v.y); o.z = f2bf(v.z); o.w = f2bf(v.w);
    *reinterpret_cast<ushort4*>(&A[i*328 + c*4]) = o;
  }
  for (int flat = tid; flat < rows*10; flat += 256) {
    int i = flat / 10, c = flat % 10;
    *reinterpret_cast<unsigned*>(&A[i*328 + 300 + c*2]) = 0u;
  }
  __syncthreads();

  int wave = tid >> 6, lane = tid & 63;
  int mrow = lane & 15, quad = lane >> 4;
  // hoist all A fragments (shared by every n-tile this wave touches)
  bf16x8 af[2][10];
  #pragma unroll
  for (int sub = 0; sub < 2; sub++)
    #pragma unroll
    for (int ks = 0; ks < 10; ks++)
      af[sub][ks] = *reinterpret_cast<const bf16x8*>(
          &A[(sub*16 + mrow)*328 + ks*32 + quad*8]);

  f32x4 acc[5][2];
  #pragma unroll
  for (int a = 0; a < 5; a++)
    #pragma unroll
    for (int b2 = 0; b2 < 2; b2++)
      acc[a][b2] = f32x4{0.f,0.f,0.f,0.f};

  const ushort* Wb = Wbf + (size_t)r*20*10*64*8;
  #pragma unroll
  for (int t5 = 0; t5 < 5; t5++) {
    int nt = wave + t5*4;
    #pragma unroll
    for (int ks = 0; ks < 10; ks++) {
      bf16x8 bf = *reinterpret_cast<const bf16x8*>(&Wb[((size_t)(nt*10 + ks)*64 + lane)*8]);
      acc[t5][0] = __builtin_amdgcn_mfma_f32_16x16x32_bf16(af[0][ks], bf, acc[t5][0], 0, 0, 0);
      acc[t5][1] = __builtin_amdgcn_mfma_f32_16x16x32_bf16(af[1][ks], bf, acc[t5][1], 0, 0, 0);
    }
  }

  // epilogue: C/D layout col(n)=lane&15, row(m)=quad*4+reg
  #pragma unroll
  for (int t5 = 0; t5 < 5; t5++) {
    int nt = wave + t5*4;
    int f = nt*16 + mrow;
    if (f >= NE) continue;
    #pragma unroll
    for (int sub = 0; sub < 2; sub++) {
      #pragma unroll
      for (int reg = 0; reg < 4; reg++) {
        int ml = sub*16 + quad*4 + reg;
        if (ml < rows) {
          int code = rcode[ml];
          int cn = code & 63, bb = (code >> 6) & 255, s = code >> 14;
          int p = (cn - 1) >> 2;
          atomicAdd(&pacc[((size_t)(s*NB + bb)*16 + p)*NE + f], acc[t5][sub][reg]);
        }
      }
    }
  }
}

// Parent update: sum = pacc (transformed children) + identity children,
// h[p] = relu(h[p] * sum/nc).
__global__ __launch_bounds__(256)
void k_parent(const int* __restrict__ prel, const int* __restrict__ hrel,
              float* __restrict__ h, const float* __restrict__ pacc, int p0) {
  int p = p0 + blockIdx.x;
  int b = blockIdx.y, s = blockIdx.z;
  int nc = min(4, 63 - 4*p);
  const int* rel = (s ? hrel : prel) + b*NN;
  size_t hb = (size_t)(s*NB + b)*NN;
  float inv = 1.0f / (float)nc;
  for (int f = threadIdx.x; f < NE; f += 256) {
    float sum = pacc[((size_t)(s*NB + b)*16 + p)*NE + f];
    for (int j = 0; j < nc; j++) {
      int c = 4*p + 1 + j;
      int r = rel[c];
      if (r < 0 || r > 2) sum += h[(hb + c)*NE + f];
    }
    float mean = sum * inv;
    float hp = h[(hb + p)*NE + f];
    float v = hp * mean;
    h[(hb + p)*NE + f] = v > 0.f ? v : 0.f;
  }
}

// Build x = [p_rep, h_rep, p-h, p*h, psg-hsg, psg*hsg]
__global__ __launch_bounds__(256)
void k_concat(const float* __restrict__ rep, const float* __restrict__ h,
              float* __restrict__ x) {
  int t = blockIdx.x*256 + threadIdx.x;
  if (t >= NB*6*NE) return;
  int b = t / (6*NE), k = t % (6*NE);
  int seg = k / NE, e = k % NE;
  float pr = rep[(size_t)b*NE + e];
  float hr = rep[(size_t)(NB + b)*NE + e];
  float ps = h[((size_t)b*NN)*NE + e];
  float hs = h[((size_t)(NB + b)*NN)*NE + e];
  float v;
  switch (seg) {
    case 0: v = pr; break;
    case 1: v = hr; break;
    case 2: v = pr - hr; break;
    case 3: v = pr * hr; break;
    case 4: v = ps - hs; break;
    default: v = ps * hs; break;
  }
  x[t] = v;
}

// Split-K FC partial: block = 64b x 64j tile, thread = 4b x 4j, K-chunk per z.
// Partials atomicAdd onto bias-initialized out. relu applied on INPUT load.
__global__ __launch_bounds__(256)
void k_fc(const float* __restrict__ in, const float* __restrict__ WTm,
          float* __restrict__ out, int K, int kc, int relu_in) {
  __shared__ __align__(16) float xl[225*68];
  int b0 = blockIdx.x * 64;
  int j0 = blockIdx.y * 64;
  int k0 = blockIdx.z * kc;
  int tid = threadIdx.x;
  for (int flat = tid; flat < kc*64; flat += 256) {
    int bbp = flat / kc, k = flat % kc;
    float v = in[(size_t)(b0 + bbp)*K + k0 + k];
    if (relu_in) v = fmaxf(v, 0.f);
    xl[k*68 + bbp] = v;
  }
  __syncthreads();
  int tj = tid & 15, tb = tid >> 4;
  int j = j0 + tj*4;
  if (j + 3 >= NH) return;
  float acc[4][4];
  #pragma unroll
  for (int a = 0; a < 4; a++)
    #pragma unroll
    for (int bq = 0; bq < 4; bq++) acc[a][bq] = 0.f;
  for (int k = 0; k < kc; k++) {
    const float4 w  = *reinterpret_cast<const float4*>(&WTm[(size_t)(k0 + k)*NH + j]);
    const float4 xv = *reinterpret_cast<const float4*>(&xl[k*68 + tb*4]);
    acc[0][0] += xv.x*w.x; acc[0][1] += xv.x*w.y; acc[0][2] += xv.x*w.z; acc[0][3] += xv.x*w.w;
    acc[1][0] += xv.y*w.x; acc[1][1] += xv.y*w.y; acc[1][2] += xv.y*w.z; acc[1][3] += xv.y*w.w;
    acc[2][0] += xv.z*w.x; acc[2][1] += xv.z*w.y; acc[2][2] += xv.z*w.z; acc[2][3] += xv.z*w.w;
    acc[3][0] += xv.w*w.x; acc[3][1] += xv.w*w.y; acc[3][2] += xv.w*w.z; acc[3][3] += xv.w*w.w;
  }
  #pragma unroll
  for (int bi = 0; bi < 4; bi++) {
    #pragma unroll
    for (int ji = 0; ji < 4; ji++) {
      atomicAdd(&out[(size_t)(b0 + tb*4 + bi)*NH + j + ji], acc[bi][ji]);
    }
  }
}

// Final 600->3 layer; one wave per batch row; relu(h3) folded into load.
__global__ __launch_bounds__(64)
void k_out(const float* __restrict__ h3, const float* __restrict__ Wout,
           const float* __restrict__ bout, float* __restrict__ out) {
  int b = blockIdx.x, tid = threadIdx.x;
  float a0 = 0.f, a1 = 0.f, a2 = 0.f;
  for (int k = tid; k < NH; k += 64) {
    float xv = fmaxf(h3[(size_t)b*NH + k], 0.f);
    a0 += xv * Wout[k];
    a1 += xv * Wout[NH + k];
    a2 += xv * Wout[2*NH + k];
  }
  #pragma unroll
  for (int off = 32; off > 0; off >>= 1) {
    a0 += __shfl_down(a0, off, 64);
    a1 += __shfl_down(a1, off, 64);
    a2 += __shfl_down(a2, off, 64);
  }
  if (tid == 0) {
    out[b*3 + 0] = a0 + bout[0];
    out[b*3 + 1] = a1 + bout[1];
    out[b*3 + 2] = a2 + bout[2];
  }
}

// ---------------- launch ----------------
extern "C" void kernel_launch(void* const* d_in, const int* in_sizes, int n_in,
                              void* d_out, int out_size, void* d_ws, size_t ws_size,
                              hipStream_t stream) {
  const int*   px    = (const int*)d_in[0];
  const int*   hx    = (const int*)d_in[1];
  const int*   pwi   = (const int*)d_in[2];
  const int*   prel  = (const int*)d_in[3];
  const int*   hwi   = (const int*)d_in[4];
  const int*   hrel  = (const int*)d_in[5];
  // d_in[6]=parent, d_in[7]=level: fixed 4-ary tree, hardcoded
  const float* Etab  = (const float*)d_in[8];
  const float* Wenc  = (const float*)d_in[9];
  const float* W0w   = (const float*)d_in[10];
  const float* W0b   = (const float*)d_in[11];
  const float* W1w   = (const float*)d_in[12];
  const float* W1b   = (const float*)d_in[13];
  const float* W2w   = (const float*)d_in[14];
  const float* W2b   = (const float*)d_in[15];
  const float* Woutw = (const float*)d_in[16];
  const float* Woutb = (const float*)d_in[17];

  float* ws   = (float*)d_ws;
  float* h    = ws + OFF_H;
  float* pacc = ws + OFF_PACC;
  float* rep  = ws + OFF_REP;
  ushort* Wbf = (ushort*)(ws + OFF_WBF);
  float* W0T  = ws + OFF_W0T;
  float* W1T  = ws + OFF_W1T;
  float* W2T  = ws + OFF_W2T;
  float* xb   = ws + OFF_X;
  float* h1   = ws + OFF_H1;
  float* h2   = ws + OFF_H2;
  float* h3   = ws + OFF_H3;
  int* lists  = (int*)(ws + OFF_LIST);
  int* cnt    = (int*)(ws + OFF_CNT);
  float* outp = (float*)d_out;

  dim3 blk(256);
  constexpr int PREP_ITEMS = PACC4 + 3*BIAS4 + NSWZ + CNT_TOT;
  k_prep<<<dim3((PREP_ITEMS + 255)/256), blk, 0, stream>>>(
      Wenc, W0b, W1b, W2b, pacc, h1, h2, h3, Wbf, cnt);
  k_list<<<dim3(126), blk, 0, stream>>>(prel, hrel, lists, cnt);
  k_transpose<<<dim3(57, 19, 3), blk, 0, stream>>>(W0w, W1w, W2w, W0T, W1T, W2T);
  k_gather<<<dim3(NB, 2), dim3(320), 0, stream>>>(px, hx, pwi, hwi, Etab, h, rep);

  // level-synchronous bottom-up: l=3,2,1 (list idx 0,1,2)
  const int nls[3] = {43, 16, 4};
  const int p0s[3] = {5, 1, 0};
  const int nps[3] = {11, 4, 1};
  for (int li = 0; li < 3; li++) {
    int tot = 2*NB*nls[li];
    k_gemm<<<dim3((tot + 31)/32, 3), blk, 0, stream>>>(h, Wbf, lists, cnt, pacc, li);
    k_parent<<<dim3(nps[li], NB, 2), blk, 0, stream>>>(prel, hrel, h, pacc, p0s[li]);
  }

  k_concat<<<dim3((NB*6*NE + 255)/256), blk, 0, stream>>>(rep, h, xb);

  k_fc<<<dim3(4, 10, 8), blk, 0, stream>>>(xb, W0T, h1, 6*NE, 225, 0);
  k_fc<<<dim3(4, 10, 4), blk, 0, stream>>>(h1, W1T, h2, NH, 150, 1);
  k_fc<<<dim3(4, 10, 4), blk, 0, stream>>>(h2, W2T, h3, NH, 150, 1);
  k_out<<<dim3(NB), dim3(64), 0, stream>>>(h3, Woutw, Woutb, outp);
}

// Round 4
// 447.963 us; speedup vs baseline: 1.6605x; 1.0029x over previous
//
#include <hip/hip_runtime.h>

constexpr int NB = 256;   // batch
constexpr int NS = 64;    // seq len
constexpr int NN = 64;    // tree nodes
constexpr int NE = 300;   // embedding dim
constexpr int NH = 600;   // hidden dim

typedef __attribute__((ext_vector_type(8))) short bf16x8;
typedef __attribute__((ext_vector_type(4))) float f32x4;

// per-(level,rel) list capacities: level idx 0 => tree level 3 (children 21..63),
// 1 => level 2 (5..20), 2 => level 1 (1..4)
__device__ __host__ constexpr int cap_of(int li)  { return li==0 ? 22016 : (li==1 ? 8192 : 2048); }
__device__ __host__ constexpr int base_of(int li) { return li==0 ? 0 : (li==1 ? 66048 : 90624); }
constexpr int LIST_TOT = 96768;  // 3*22016 + 3*8192 + 3*2048
constexpr int CNT_TOT  = 9*32;   // 9 counters padded to separate cache lines

// ---------------- workspace layout (float-indexed) ----------------
constexpr size_t OFF_H    = 0;                          // h state fp32 [2][NB][NN][NE]
constexpr size_t SZ_H     = (size_t)2*NB*NN*NE;
constexpr size_t OFF_T    = OFF_H + SZ_H;               // transformed child rows, same shape
constexpr size_t SZ_T     = (size_t)2*NB*NN*NE;
constexpr size_t OFF_REP  = OFF_T + SZ_T;               // bag-of-words rep [2][NB][NE]
constexpr size_t SZ_REP   = (size_t)2*NB*NE;
constexpr size_t OFF_WBF  = OFF_REP + SZ_REP;           // W_enc bf16 B-frag swizzled
constexpr size_t SZ_WBF   = (size_t)3*20*10*64*8/2;     // 307200 ushorts = 153600 floats
constexpr size_t OFF_W0T  = OFF_WBF + SZ_WBF;           // W0^T [1800][600]
constexpr size_t SZ_W0T   = (size_t)6*NE*NH;
constexpr size_t OFF_W1T  = OFF_W0T + SZ_W0T;           // W1^T [600][600]
constexpr size_t SZ_W1T   = (size_t)NH*NH;
constexpr size_t OFF_W2T  = OFF_W1T + SZ_W1T;           // W2^T [600][600]
constexpr size_t SZ_W2T   = (size_t)NH*NH;
constexpr size_t OFF_H1   = OFF_W2T + SZ_W2T;           // [NB][NH]
constexpr size_t OFF_H2   = OFF_H1 + (size_t)NB*NH;
constexpr size_t OFF_H3   = OFF_H2 + (size_t)NB*NH;
constexpr size_t OFF_LIST = OFF_H3 + (size_t)NB*NH;     // int [LIST_TOT]
constexpr size_t OFF_CNT  = OFF_LIST + LIST_TOT;        // int [CNT_TOT]

__device__ __forceinline__ ushort f2bf(float x) {
  unsigned u = __float_as_uint(x);
  unsigned r = (u + 0x7FFFu + ((u >> 16) & 1u)) >> 16;   // RNE
  return (ushort)r;
}

// ---------------- kernels ----------------

// Fused setup: [prep items: bias-init h1/h2/h3, swizzle W_enc, zero cnt]
// then [transpose tiles for W0/W1/W2].
constexpr int BIAS4 = NB*NH/4;            // 38400 float4 per layer
constexpr int NSWZ  = 3*20*10*64;         // 38400 lane-frags
constexpr int PREP_ITEMS  = 3*BIAS4 + NSWZ + CNT_TOT;            // 153888
constexpr int PREP_BLOCKS = (PREP_ITEMS + 255)/256;              // 602
constexpr int TR_BLOCKS   = 57*19*3;                             // 3249
constexpr int SETUP_BLOCKS = PREP_BLOCKS + TR_BLOCKS;

__global__ __launch_bounds__(256)
void k_setup(const float* __restrict__ Wenc, const float* __restrict__ b0,
             const float* __restrict__ b1, const float* __restrict__ b2,
             const float* __restrict__ W0, const float* __restrict__ W1,
             const float* __restrict__ W2,
             float* __restrict__ h1, float* __restrict__ h2, float* __restrict__ h3,
             ushort* __restrict__ Wbf, int* __restrict__ cnt,
             float* __restrict__ W0T, float* __restrict__ W1T, float* __restrict__ W2T) {
  __shared__ float tile[32][33];
  if (blockIdx.x < PREP_BLOCKS) {
    int t = blockIdx.x*256 + threadIdx.x;
    if (t < 3*BIAS4) {
      int layer = t / BIAS4, i = t % BIAS4;
      const float* b = layer==0 ? b0 : (layer==1 ? b1 : b2);
      float* hx = layer==0 ? h1 : (layer==1 ? h2 : h3);
      reinterpret_cast<float4*>(hx)[i] = reinterpret_cast<const float4*>(b)[i % 150];
      return;
    }
    t -= 3*BIAS4;
    if (t < NSWZ) {
      // Wbf[((nt*10+ks)*64+lane)*8 + j] = bf16(W_enc[r][f][e]),
      // f = nt*16+(lane&15), e = ks*32+(lane>>4)*8+j, zero-padded past 300.
      int lane = t & 63, rest = t >> 6;
      int ks = rest % 10, rnt = rest / 10, nt = rnt % 20, r = rnt / 20;
      int f = nt*16 + (lane & 15), e0 = ks*32 + (lane >> 4)*8;
      ushort v[8];
      #pragma unroll
      for (int j = 0; j < 8; j++) {
        int e = e0 + j;
        v[j] = (f < NE && e < NE) ? f2bf(Wenc[((size_t)r*NE + f)*NE + e]) : (ushort)0;
      }
      *reinterpret_cast<int4*>(&Wbf[(size_t)t*8]) = *reinterpret_cast<const int4*>(v);
      return;
    }
    t -= NSWZ;
    if (t < CNT_TOT) cnt[t] = 0;
    return;
  }
  // transpose tiles
  int idx = blockIdx.x - PREP_BLOCKS;
  int z = idx / (57*19), rem = idx % (57*19);
  int by = rem / 57, bx = rem % 57;
  const float* W = z==0 ? W0 : (z==1 ? W1 : W2);
  float* WT = z==0 ? W0T : (z==1 ? W1T : W2T);
  int K = z==0 ? 1800 : 600;               // W [600][K] -> WT [K][600]
  int k0 = bx * 32, j0 = by * 32;
  if (k0 >= K) return;
  int tx = threadIdx.x & 31, ty = threadIdx.x >> 5;
  for (int yy = ty; yy < 32; yy += 8) {
    int j = j0 + yy, k = k0 + tx;
    if (j < 600 && k < K) tile[yy][tx] = W[(size_t)j*K + k];
  }
  __syncthreads();
  for (int yy = ty; yy < 32; yy += 8) {
    int k = k0 + yy, j = j0 + tx;
    if (k < K && j < 600) WT[(size_t)k*600 + j] = tile[tx][yy];
  }
}

// One block per (b, side), 320 threads. Stage 64 seq-embedding rows in LDS,
// accumulate rep, build word/h state from LDS (broadcast reads).
__global__ __launch_bounds__(320)
void k_gather(const int* __restrict__ px, const int* __restrict__ hx,
              const int* __restrict__ pwi, const int* __restrict__ hwi,
              const float* __restrict__ Etab, float* __restrict__ h,
              float* __restrict__ rep) {
  int b = blockIdx.x, s = blockIdx.y, tid = threadIdx.x;
  const int* xs = (s ? hx : px) + b*NS;
  const int* wi = (s ? hwi : pwi) + b*NN;
  __shared__ float Es[64*300];     // 76.8 KB
  __shared__ int xsh[NS];
  __shared__ int wish[NN];
  if (tid < NS) xsh[tid] = xs[tid];
  else if (tid >= 64 && tid < 64 + NN) wish[tid - 64] = wi[tid - 64];
  __syncthreads();
  for (int flat = tid; flat < 64*75; flat += 320) {
    int row = flat / 75, c = flat % 75;
    const float4 v = *reinterpret_cast<const float4*>(&Etab[(size_t)xsh[row]*NE + c*4]);
    *reinterpret_cast<float4*>(&Es[row*NE + c*4]) = v;
  }
  __syncthreads();
  int e = tid;
  if (e >= NE) return;
  float acc = 0.f;
  #pragma unroll 8
  for (int j = 0; j < NS; j++) acc += Es[j*NE + e];
  rep[(size_t)(s*NB + b)*NE + e] = acc;
  size_t hb = (size_t)(s*NB + b)*NN;
  for (int n = 0; n < NN; n++) {
    int w = wish[n];
    float v = (w < 0) ? 1.0f : Es[w*NE + e];
    h[(hb + n)*NE + e] = v;
  }
}

// Compact transformed children of ALL levels into per-(level,rel) lists.
// Wave-aggregated: one atomic per (wave, non-empty bucket).
__global__ __launch_bounds__(256)
void k_list(const int* __restrict__ prel, const int* __restrict__ hrel,
            int* __restrict__ lists, int* __restrict__ cnt) {
  int t = blockIdx.x*256 + threadIdx.x;   // exactly 2*256*63 = 32256 threads
  int c = 1 + (t % 63);
  int b = (t / 63) % NB;
  int s = t / (63*NB);
  int r = (s ? hrel : prel)[b*NN + c];
  int li = (c >= 21) ? 0 : (c >= 5 ? 1 : 2);
  int bucket = (r >= 0 && r <= 2) ? li*3 + r : -1;
  int code = (s << 14) | (b << 6) | c;
  int lane = threadIdx.x & 63;
  #pragma unroll
  for (int k = 0; k < 9; k++) {
    unsigned long long mask = __ballot(bucket == k);
    if (mask == 0ull) continue;                       // wave-uniform
    int leader = __ffsll((unsigned long long)mask) - 1;
    int base = 0;
    if (lane == leader) base = atomicAdd(&cnt[k*32], (int)__popcll(mask));
    base = __shfl(base, leader, 64);
    if (bucket == k) {
      int pos = base + (int)__popcll(mask & ((1ull << lane) - 1ull));
      lists[base_of(k/3) + (k%3)*cap_of(k/3) + pos] = code;
    }
  }
}

// MFMA gathered GEMM: 32 listed rows x 320(f,padded) per block, K=320 padded.
// A: h rows fp32->bf16 staged in LDS (row stride 328 -> free 2-way bank alias).
// B: pre-swizzled bf16 frags, one coalesced 16B global load per lane per MFMA.
// Output: PLAIN stores into dense T rows (each listed row owns its T row;
// summed later by k_parent -> no atomics, no zero-init).
__global__ __launch_bounds__(256)
void k_gemm(const float* __restrict__ h, const ushort* __restrict__ Wbf,
            const int* __restrict__ lists, const int* __restrict__ cnt,
            float* __restrict__ T, int lvl) {
  int r = blockIdx.y;
  int M = cnt[(lvl*3 + r)*32];
  int i0 = blockIdx.x * 32;
  if (i0 >= M) return;
  int rows = min(32, M - i0);
  __shared__ ushort A[32*328];
  __shared__ int rcode[32];
  int tid = threadIdx.x;
  if (tid < rows) rcode[tid] = lists[base_of(lvl) + r*cap_of(lvl) + i0 + tid];
  __syncthreads();
  // stage A: fp32 -> bf16, 4 elems per chunk; zero K-pad region e in [300,320)
  for (int flat = tid; flat < rows*75; flat += 256) {
    int i = flat / 75, c = flat % 75;
    int code = rcode[i];
    int cn = code & 63, bb = (code >> 6) & 255, s = code >> 14;
    const float4 v = *reinterpret_cast<const float4*>(
        &h[((size_t)(s*NB + bb)*NN + cn)*NE + c*4]);
    ushort4 o; o.x = f2bf(v.x); o.y = f2bf(v.y); o.z = f2bf(v.z); o.w = f2bf(v.w);
    *reinterpret_cast<ushort4*>(&A[i*328 + c*4]) = o;
  }
  for (int flat = tid; flat < rows*10; flat += 256) {
    int i = flat / 10, c = flat % 10;
    *reinterpret_cast<unsigned*>(&A[i*328 + 300 + c*2]) = 0u;
  }
  __syncthreads();

  int wave = tid >> 6, lane = tid & 63;
  int mrow = lane & 15, quad = lane >> 4;
  // hoist all A fragments (shared by every n-tile this wave touches)
  bf16x8 af[2][10];
  #pragma unroll
  for (int sub = 0; sub < 2; sub++)
    #pragma unroll
    for (int ks = 0; ks < 10; ks++)
      af[sub][ks] = *reinterpret_cast<const bf16x8*>(
          &A[(sub*16 + mrow)*328 + ks*32 + quad*8]);

  f32x4 acc[5][2];
  #pragma unroll
  for (int a = 0; a < 5; a++)
    #pragma unroll
    for (int b2 = 0; b2 < 2; b2++)
      acc[a][b2] = f32x4{0.f,0.f,0.f,0.f};

  const ushort* Wb = Wbf + (size_t)r*20*10*64*8;
  #pragma unroll
  for (int t5 = 0; t5 < 5; t5++) {
    int nt = wave + t5*4;
    #pragma unroll
    for (int ks = 0; ks < 10; ks++) {
      bf16x8 bf = *reinterpret_cast<const bf16x8*>(&Wb[((size_t)(nt*10 + ks)*64 + lane)*8]);
      acc[t5][0] = __builtin_amdgcn_mfma_f32_16x16x32_bf16(af[0][ks], bf, acc[t5][0], 0, 0, 0);
      acc[t5][1] = __builtin_amdgcn_mfma_f32_16x16x32_bf16(af[1][ks], bf, acc[t5][1], 0, 0, 0);
    }
  }

  // epilogue: C/D layout col(n)=lane&15, row(m)=quad*4+reg; plain coalesced stores
  #pragma unroll
  for (int t5 = 0; t5 < 5; t5++) {
    int nt = wave + t5*4;
    int f = nt*16 + mrow;
    if (f >= NE) continue;
    #pragma unroll
    for (int sub = 0; sub < 2; sub++) {
      #pragma unroll
      for (int reg = 0; reg < 4; reg++) {
        int ml = sub*16 + quad*4 + reg;
        if (ml < rows) {
          int code = rcode[ml];
          int cn = code & 63, bb = (code >> 6) & 255, s = code >> 14;
          T[((size_t)(s*NB + bb)*NN + cn)*NE + f] = acc[t5][sub][reg];
        }
      }
    }
  }
}

// Parent update: sum over children of (rel in 0..2 ? T[c] : h[c]);
// h[p] = relu(h[p] * sum/nc).
__global__ __launch_bounds__(320)
void k_parent(const int* __restrict__ prel, const int* __restrict__ hrel,
              float* __restrict__ h, const float* __restrict__ T, int p0) {
  int p = p0 + blockIdx.x;
  int b = blockIdx.y, s = blockIdx.z;
  int nc = min(4, 63 - 4*p);   // parent 15 has 3 children; all others 4
  const int* rel = (s ? hrel : prel) + b*NN;
  size_t hb = (size_t)(s*NB + b)*NN;
  float inv = 1.0f / (float)nc;
  int f = threadIdx.x;
  if (f >= NE) return;
  float sum = 0.f;
  for (int j = 0; j < nc; j++) {
    int c = 4*p + 1 + j;
    int r = rel[c];   // wave-uniform
    const float* src = (r >= 0 && r <= 2) ? T : h;
    sum += src[(hb + c)*NE + f];
  }
  float mean = sum * inv;
  float hp = h[(hb + p)*NE + f];
  float v = hp * mean;
  h[(hb + p)*NE + f] = v > 0.f ? v : 0.f;
}

// Split-K FC partial: block = 64b x 64j tile, thread = 4b x 4j, K-chunk per z.
// Partials atomicAdd onto bias-initialized out.
// mode 0: plain input; mode 1: relu(input); mode 2: build concat feature
// x = [p_rep, h_rep, p-h, p*h, psg-hsg, psg*hsg] on the fly from rep/h.
__global__ __launch_bounds__(256)
void k_fc(const float* __restrict__ in, const float* __restrict__ WTm,
          float* __restrict__ out, int K, int kc, int mode,
          const float* __restrict__ rep, const float* __restrict__ h) {
  __shared__ __align__(16) float xl[225*68];
  int b0 = blockIdx.x * 64;
  int j0 = blockIdx.y * 64;
  int k0 = blockIdx.z * kc;
  int tid = threadIdx.x;
  if (mode == 2) {
    for (int flat = tid; flat < kc*64; flat += 256) {
      int bbp = flat / kc, k = flat % kc;
      int kg = k0 + k;
      int seg = kg / NE, e = kg % NE;
      int b = b0 + bbp;
      float v;
      switch (seg) {
        case 0: v = rep[(size_t)b*NE + e]; break;
        case 1: v = rep[(size_t)(NB + b)*NE + e]; break;
        case 2: v = rep[(size_t)b*NE + e] - rep[(size_t)(NB + b)*NE + e]; break;
        case 3: v = rep[(size_t)b*NE + e] * rep[(size_t)(NB + b)*NE + e]; break;
        case 4: v = h[(size_t)b*NN*NE + e] - h[(size_t)(NB + b)*NN*NE + e]; break;
        default: v = h[(size_t)b*NN*NE + e] * h[(size_t)(NB + b)*NN*NE + e]; break;
      }
      xl[k*68 + bbp] = v;
    }
  } else {
    for (int flat = tid; flat < kc*64; flat += 256) {
      int bbp = flat / kc, k = flat % kc;
      float v = in[(size_t)(b0 + bbp)*K + k0 + k];
      if (mode == 1) v = fmaxf(v, 0.f);
      xl[k*68 + bbp] = v;
    }
  }
  __syncthreads();
  int tj = tid & 15, tb = tid >> 4;
  int j = j0 + tj*4;
  if (j + 3 >= NH) return;   // tail j-tile
  float acc[4][4];
  #pragma unroll
  for (int a = 0; a < 4; a++)
    #pragma unroll
    for (int bq = 0; bq < 4; bq++) acc[a][bq] = 0.f;
  for (int k = 0; k < kc; k++) {
    const float4 w  = *reinterpret_cast<const float4*>(&WTm[(size_t)(k0 + k)*NH + j]);
    const float4 xv = *reinterpret_cast<const float4*>(&xl[k*68 + tb*4]);
    acc[0][0] += xv.x*w.x; acc[0][1] += xv.x*w.y; acc[0][2] += xv.x*w.z; acc[0][3] += xv.x*w.w;
    acc[1][0] += xv.y*w.x; acc[1][1] += xv.y*w.y; acc[1][2] += xv.y*w.z; acc[1][3] += xv.y*w.w;
    acc[2][0] += xv.z*w.x; acc[2][1] += xv.z*w.y; acc[2][2] += xv.z*w.z; acc[2][3] += xv.z*w.w;
    acc[3][0] += xv.w*w.x; acc[3][1] += xv.w*w.y; acc[3][2] += xv.w*w.z; acc[3][3] += xv.w*w.w;
  }
  #pragma unroll
  for (int bi = 0; bi < 4; bi++) {
    #pragma unroll
    for (int ji = 0; ji < 4; ji++) {
      atomicAdd(&out[(size_t)(b0 + tb*4 + bi)*NH + j + ji], acc[bi][ji]);
    }
  }
}

// Final 600->3 layer; one wave per batch row; relu(h3) folded into load.
__global__ __launch_bounds__(64)
void k_out(const float* __restrict__ h3, const float* __restrict__ Wout,
           const float* __restrict__ bout, float* __restrict__ out) {
  int b = blockIdx.x, tid = threadIdx.x;
  float a0 = 0.f, a1 = 0.f, a2 = 0.f;
  for (int k = tid; k < NH; k += 64) {
    float xv = fmaxf(h3[(size_t)b*NH + k], 0.f);
    a0 += xv * Wout[k];
    a1 += xv * Wout[NH + k];
    a2 += xv * Wout[2*NH + k];
  }
  #pragma unroll
  for (int off = 32; off > 0; off >>= 1) {
    a0 += __shfl_down(a0, off, 64);
    a1 += __shfl_down(a1, off, 64);
    a2 += __shfl_down(a2, off, 64);
  }
  if (tid == 0) {
    out[b*3 + 0] = a0 + bout[0];
    out[b*3 + 1] = a1 + bout[1];
    out[b*3 + 2] = a2 + bout[2];
  }
}

// ---------------- launch ----------------
extern "C" void kernel_launch(void* const* d_in, const int* in_sizes, int n_in,
                              void* d_out, int out_size, void* d_ws, size_t ws_size,
                              hipStream_t stream) {
  const int*   px    = (const int*)d_in[0];
  const int*   hx    = (const int*)d_in[1];
  const int*   pwi   = (const int*)d_in[2];
  const int*   prel  = (const int*)d_in[3];
  const int*   hwi   = (const int*)d_in[4];
  const int*   hrel  = (const int*)d_in[5];
  // d_in[6]=parent, d_in[7]=level: fixed 4-ary tree, hardcoded
  const float* Etab  = (const float*)d_in[8];
  const float* Wenc  = (const float*)d_in[9];
  const float* W0w   = (const float*)d_in[10];
  const float* W0b   = (const float*)d_in[11];
  const float* W1w   = (const float*)d_in[12];
  const float* W1b   = (const float*)d_in[13];
  const float* W2w   = (const float*)d_in[14];
  const float* W2b   = (const float*)d_in[15];
  const float* Woutw = (const float*)d_in[16];
  const float* Woutb = (const float*)d_in[17];

  float* ws   = (float*)d_ws;
  float* h    = ws + OFF_H;
  float* T    = ws + OFF_T;
  float* rep  = ws + OFF_REP;
  ushort* Wbf = (ushort*)(ws + OFF_WBF);
  float* W0T  = ws + OFF_W0T;
  float* W1T  = ws + OFF_W1T;
  float* W2T  = ws + OFF_W2T;
  float* h1   = ws + OFF_H1;
  float* h2   = ws + OFF_H2;
  float* h3   = ws + OFF_H3;
  int* lists  = (int*)(ws + OFF_LIST);
  int* cnt    = (int*)(ws + OFF_CNT);
  float* outp = (float*)d_out;

  dim3 blk(256);
  k_setup<<<dim3(SETUP_BLOCKS), blk, 0, stream>>>(
      Wenc, W0b, W1b, W2b, W0w, W1w, W2w, h1, h2, h3, Wbf, cnt, W0T, W1T, W2T);
  k_list<<<dim3(126), blk, 0, stream>>>(prel, hrel, lists, cnt);
  k_gather<<<dim3(NB, 2), dim3(320), 0, stream>>>(px, hx, pwi, hwi, Etab, h, rep);

  // level-synchronous bottom-up: tree levels 3,2,1 (list idx 0,1,2)
  const int nls[3] = {43, 16, 4};
  const int p0s[3] = {5, 1, 0};
  const int nps[3] = {11, 4, 1};
  for (int li = 0; li < 3; li++) {
    int tot = 2*NB*nls[li];
    k_gemm<<<dim3((tot + 31)/32, 3), blk, 0, stream>>>(h, Wbf, lists, cnt, T, li);
    k_parent<<<dim3(nps[li], NB, 2), dim3(320), 0, stream>>>(prel, hrel, h, T, p0s[li]);
  }

  k_fc<<<dim3(4, 10, 8), blk, 0, stream>>>(nullptr, W0T, h1, 6*NE, 225, 2, rep, h);
  k_fc<<<dim3(4, 10, 4), blk, 0, stream>>>(h1, W1T, h2, NH, 150, 1, nullptr, nullptr);
  k_fc<<<dim3(4, 10, 4), blk, 0, stream>>>(h2, W2T, h3, NH, 150, 1, nullptr, nullptr);
  k_out<<<dim3(NB), dim3(64), 0, stream>>>(h3, Woutw, Woutb, outp);
}